// Round 4
// baseline (376.756 us; speedup 1.0000x reference)
//
#include <hip/hip_runtime.h>

// MultiCellLSTM: B=4096 chains, H=64, T=512, types by t%4 = (0,2,1,2).
// R4: 8 waves (512 thr) per block of 16 batch rows -> 2 waves/SIMD for
// latency hiding. Wave (p = wid&3, u = wid>>2) computes gate-pair {2u,2u+1}
// for h-cols 16p..16p+15 (6 MFMAs), activates them (wave-uniform consts),
// and writes float2 gate-pairs to act[u][m][h] (HP=65 odd stride).
// After barrier2, EVERY wave updates 2 cells/lane (rows u*8+q, u*8+4+q;
// col 16p+c): cx register-local, 4 ds_read_b64 fetch all 4 gates.
// Single A buffer (reads end before barrier2; writes after), 2 barriers/step.

typedef __attribute__((ext_vector_type(8))) short short8v;
typedef __attribute__((ext_vector_type(4))) float float4v;
typedef __attribute__((ext_vector_type(2))) float float2v;

template <int N> struct IC { static constexpr int value = N; };

#define AST 72   // shorts per A row (64 hx + pad); frags 16B aligned
#define HP 65    // act h-stride in float2 units (odd -> spread banks)
#define PLANE (16 * HP)
#define XS1 516  // x LDS row strides (conflict-avoiding padding)
#define XS2 260
#define XS3 132

#if __has_builtin(__builtin_amdgcn_exp2f)
#define EXP2F(x) __builtin_amdgcn_exp2f(x)
#else
#define EXP2F(x) exp2f(x)
#endif
#if __has_builtin(__builtin_amdgcn_rcpf)
#define RCPF(x) __builtin_amdgcn_rcpf(x)
#else
#define RCPF(x) (1.0f / (x))
#endif

#define NL2E -1.4426950408889634f   // -log2(e)
#define NL2E2 -2.8853900817779268f  // -2*log2(e)

__device__ __forceinline__ short f2bf(float f) {
  union { float f; unsigned u; } v; v.f = f;
  unsigned r = v.u + 0x7FFFu + ((v.u >> 16) & 1u);  // RNE
  return (short)(r >> 16);
}
__device__ __forceinline__ float bf2f(short h) {
  union { float f; unsigned u; } v;
  v.u = ((unsigned)(unsigned short)h) << 16;
  return v.f;
}
__device__ __forceinline__ float rcp1p(float y) {  // 1/(1+exp2(y))
  return RCPF(1.0f + EXP2F(y));
}
__device__ __forceinline__ float fsig(float x) { return rcp1p(x * NL2E); }

__global__ __launch_bounds__(512, 2) void mlstm_kernel(
    const float* __restrict__ x1, const float* __restrict__ x2,
    const float* __restrict__ x3,
    const float* __restrict__ Wi3, const float* __restrict__ Wh3,
    const float* __restrict__ bi3, const float* __restrict__ bh3,
    const float* __restrict__ Wi2, const float* __restrict__ Wh2,
    const float* __restrict__ bi2, const float* __restrict__ bh2,
    const float* __restrict__ Wi1, const float* __restrict__ Wh1,
    const float* __restrict__ bi1, const float* __restrict__ bh1,
    const float* __restrict__ Wout, const float* __restrict__ bout,
    float* __restrict__ out) {
  __shared__ __attribute__((aligned(16))) short Ab[16 * AST];
  __shared__ __attribute__((aligned(16))) float2v actb[2 * PLANE];
  __shared__ short x1b[16 * XS1];
  __shared__ short x2b[16 * XS2];
  __shared__ short x3b[16 * XS3];

  const int tid = threadIdx.x;  // 0..511
  const int wid = tid >> 6;     // 0..7
  const int lane = tid & 63;
  const int q = lane >> 4;
  const int c = lane & 15;
  const int p = wid & 3;   // col-slice
  const int u = wid >> 2;  // gate-half: 0 -> gates i,f ; 1 -> gates g,o
  const int R0 = blockIdx.x << 4;

  // ---- preload x into LDS as bf16 ----
  for (int idx = tid; idx < 16 * 512; idx += 512) {
    int m = idx >> 9, t = idx & 511;
    x1b[m * XS1 + t] = f2bf(x1[(size_t)(R0 + m) * 512 + t]);
  }
  for (int idx = tid; idx < 16 * 256; idx += 512) {
    int m = idx >> 8, t = idx & 255;
    x2b[m * XS2 + t] = f2bf(x2[(size_t)(R0 + m) * 256 + t]);
  }
  for (int idx = tid; idx < 16 * 128; idx += 512) {
    int m = idx >> 7, t = idx & 127;
    x3b[m * XS3 + t] = f2bf(x3[(size_t)(R0 + m) * 128 + t]);
  }
  // ---- A: hx(0) = 0 ----
  for (int idx = tid; idx < 16 * AST; idx += 512) Ab[idx] = 0;

  // ---- pack scaled weights for this wave's 2 tiles: n = (2u+i)*64+16p+c ----
  // B[k][n] = s_g * Wh[n][k], k = kf*32+q*8+j ; wix: k=64..66 -> Wi cols; bias f32.
  short8v whs[3][2][2];
  short8v wix[3][2];
  float bia[3][2];
  {
    const float* WhA[3] = {Wh3, Wh2, Wh1};
    const float* WiA[3] = {Wi3, Wi2, Wi1};
    const float* biA[3] = {bi3, bi2, bi1};
    const float* bhA[3] = {bh3, bh2, bh1};
    const int wdt[3] = {3, 2, 1};
#pragma unroll
    for (int ty = 0; ty < 3; ++ty) {
#pragma unroll
      for (int i = 0; i < 2; ++i) {
        const int g = 2 * u + i;
        const float sg = (g == 2) ? NL2E2 : NL2E;
        const int n = g * 64 + 16 * p + c;
#pragma unroll
        for (int kf = 0; kf < 2; ++kf) {
          short8v v;
#pragma unroll
          for (int j = 0; j < 8; ++j)
            v[j] = f2bf(sg * WhA[ty][n * 64 + kf * 32 + q * 8 + j]);
          whs[ty][i][kf] = v;
        }
        short8v v2 = {0, 0, 0, 0, 0, 0, 0, 0};
        if (q == 0) {
#pragma unroll
          for (int j = 0; j < 3; ++j)
            if (j < wdt[ty]) v2[j] = f2bf(sg * WiA[ty][n * wdt[ty] + j]);
        }
        wix[ty][i] = v2;
        bia[ty][i] = sg * (biA[ty][n] + bhA[ty][n]);
      }
    }
  }

  // acc0 activation consts: u=0 -> sigmoid(i); u=1 -> tanh(g). acc1 always sigmoid.
  const float kA = u ? 2.0f : 1.0f;
  const float kB = u ? -1.0f : 0.0f;

  // addressing
  const int afo = c * AST + q * 8;                    // A-frag: m=c, k=q*8+j
  const int awo = u * PLANE + (4 * q) * HP + 16 * p + c;  // act write (rows 4q+r)
  const int m0 = u * 8 + q, m1 = m0 + 4;              // update-owned rows
  const int hcol = 16 * p + c;
  const int aro0 = m0 * HP + hcol, aro1 = m1 * HP + hcol;
  const int hwo0 = m0 * AST + hcol, hwo1 = m1 * AST + hcol;
  const int x1o = c * XS1, x2o = c * XS2, x3o = c * XS3;

  __syncthreads();

  float cx0 = 0.f, cx1 = 0.f;
  short px1 = x1b[x1o], px2 = x2b[x2o], px3 = x3b[x3o];  // x(0) prefetch

  auto stepf = [&](auto tyc, int t) {
    constexpr int TY = decltype(tyc)::value;
    __syncthreads();  // barrier1: A(t) complete (phase-B writes of t-1 done)
    // ---- phase A: MFMA + gate activation ----
    short8v a0 = *(const short8v*)(Ab + afo);
    short8v a1 = *(const short8v*)(Ab + afo + 32);
    short8v a2 = {px1, px2, px3, 0, 0, 0, 0, 0};
    // prefetch x(t+1) (independent of hx; hides LDS latency)
    int tn = t + 1;
    if (tn > 511) tn = 511;
    px1 = x1b[x1o + tn];
    px2 = x2b[x2o + (tn >> 1)];
    px3 = x3b[x3o + (tn >> 2)];

    float b0 = bia[TY][0], b1 = bia[TY][1];
    float4v z0 = {b0, b0, b0, b0};
    float4v z1 = {b1, b1, b1, b1};
    z0 = __builtin_amdgcn_mfma_f32_16x16x32_bf16(a0, whs[TY][0][0], z0, 0, 0, 0);
    z1 = __builtin_amdgcn_mfma_f32_16x16x32_bf16(a0, whs[TY][1][0], z1, 0, 0, 0);
    z0 = __builtin_amdgcn_mfma_f32_16x16x32_bf16(a1, whs[TY][0][1], z0, 0, 0, 0);
    z1 = __builtin_amdgcn_mfma_f32_16x16x32_bf16(a1, whs[TY][1][1], z1, 0, 0, 0);
    z0 = __builtin_amdgcn_mfma_f32_16x16x32_bf16(a2, wix[TY][0], z0, 0, 0, 0);
    z1 = __builtin_amdgcn_mfma_f32_16x16x32_bf16(a2, wix[TY][1], z1, 0, 0, 0);
#pragma unroll
    for (int r = 0; r < 4; ++r) {
      float gA = __builtin_fmaf(kA, rcp1p(z0[r]), kB);  // gate 2u
      float gB = rcp1p(z1[r]);                          // gate 2u+1 (f or o)
      float2v pr = {gA, gB};
      actb[awo + r * HP] = pr;
    }
    __syncthreads();  // barrier2: act complete
    // ---- phase B: update 2 cells/lane (rows m0, m1; col hcol) ----
    float2v if0 = actb[aro0];          // (si, sf) cell m0
    float2v go0 = actb[PLANE + aro0];  // (tg, so)
    float2v if1 = actb[aro1];
    float2v go1 = actb[PLANE + aro1];
    float n0 = __builtin_fmaf(if0.y, cx0, if0.x * go0.x);
    cx0 = n0;
    float h0 = go0.y * __builtin_fmaf(2.0f, rcp1p(n0 * NL2E2), -1.0f);
    Ab[hwo0] = f2bf(h0);
    float n1 = __builtin_fmaf(if1.y, cx1, if1.x * go1.x);
    cx1 = n1;
    float h1 = go1.y * __builtin_fmaf(2.0f, rcp1p(n1 * NL2E2), -1.0f);
    Ab[hwo1] = f2bf(h1);
  };

  // t%4 -> type: 0->0, 1->2, 2->1, 3->2
  for (int t4 = 0; t4 < 512; t4 += 4) {
    stepf(IC<0>{}, t4);
    stepf(IC<2>{}, t4 + 1);
    stepf(IC<1>{}, t4 + 2);
    stepf(IC<2>{}, t4 + 3);
  }
  __syncthreads();  // final hx in Ab

  if (tid < 16) {
    float s = bout[0];
    const short* hr = Ab + tid * AST;
#pragma unroll
    for (int k = 0; k < 64; ++k)
      s = __builtin_fmaf(bf2f(hr[k]), Wout[k], s);
    out[R0 + tid] = fsig(s);
  }
}

extern "C" void kernel_launch(void* const* d_in, const int* in_sizes, int n_in,
                              void* d_out, int out_size, void* d_ws,
                              size_t ws_size, hipStream_t stream) {
  const float* x1 = (const float*)d_in[0];
  const float* x2 = (const float*)d_in[1];
  const float* x3 = (const float*)d_in[2];
  const float* Wi3 = (const float*)d_in[3];
  const float* Wh3 = (const float*)d_in[4];
  const float* bi3 = (const float*)d_in[5];
  const float* bh3 = (const float*)d_in[6];
  const float* Wi2 = (const float*)d_in[7];
  const float* Wh2 = (const float*)d_in[8];
  const float* bi2 = (const float*)d_in[9];
  const float* bh2 = (const float*)d_in[10];
  const float* Wi1 = (const float*)d_in[11];
  const float* Wh1 = (const float*)d_in[12];
  const float* bi1 = (const float*)d_in[13];
  const float* bh1 = (const float*)d_in[14];
  const float* Wout = (const float*)d_in[15];
  const float* bout = (const float*)d_in[16];
  float* out = (float*)d_out;

  hipLaunchKernelGGL(mlstm_kernel, dim3(256), dim3(512), 0, stream,
                     x1, x2, x3, Wi3, Wh3, bi3, bh3, Wi2, Wh2, bi2, bh2,
                     Wi1, Wh1, bi1, bh1, Wout, bout, out);
}